// Round 14
// baseline (133.281 us; speedup 1.0000x reference)
//
#include <hip/hip_runtime.h>
#include <cstdint>

#define M_ROWS   100000
#define N_NODES  100000
#define NNZ_E    1600000
#define K_DIM    768
#define NCHUNK   24
#define NEG_SLOPE 0.2f
#define NBUK     391           // ceil(M/256) buckets of 256 rows
#define BCAP     5120          // bucket capacity (mean 4096 + 16 sigma)
#define EPB      8192          // edges per k_bin block
#define NTILE    3125          // 32-row tiles
#define GMAIN    1563          // k_main blocks (2 tiles each)
#define WB_ELEMS (NCHUNK * 4 * 64 * 8)   // 49152
#define NFWB_BLOCKS ((N_NODES * 16 + WB_ELEMS + 255) / 256)  // 1,649,152/256 = 6442

using f32x4 = __attribute__((ext_vector_type(4))) float;
using f16x8 = __attribute__((ext_vector_type(8))) _Float16;
using f16x4 = __attribute__((ext_vector_type(4))) _Float16;

// ---------------- workspace layout (bytes) ----------------
#define OFF_CNT    0u          // int[100352] true counts (k_sortbucket)
#define OFF_RS     401408u     // int[100352] bucket-strided row starts
#define OFF_PART   802816u     // float[512]
#define OFF_DELTA  804864u     // float (pad 256)
#define OFF_GCUR   805120u     // int[512]
#define OFF_BINCSR 807168u     // int[NBUK*BCAP]: k_bin packed edges, then in-place CSR
#define OFF_WB     8814848u    // _Float16[49152]
#define OFF_NFH    8913152u    // _Float16[N*64] = 12.8 MB (128B-aligned rows)
#define WS_NEEDED  21713152u

// -------- K0 (fallback path only): pack W into f16 B-fragments --------
__global__ void k_wb(const float* __restrict__ W, _Float16* __restrict__ Wb) {
  int idx = blockIdx.x * blockDim.x + threadIdx.x;
  if (idx < WB_ELEMS) {
    int i  = idx & 7;
    int l  = (idx >> 3) & 63;
    int n  = (idx >> 9) & 3;
    int kc = idx >> 11;
    int k  = kc * 32 + ((l >> 4) << 3) + i;
    int o  = n * 16 + (l & 15);
    Wb[idx] = (_Float16)W[o * K_DIM + k];
  }
}

// -------- K0b (f16 path): nf->f16 + Wb pack + gcur seed, one kernel.
//          Grid MUST supply 1,600,000 + 49,152 threads (bug in r7/r8/r13:
//          only 12,288 Wb writers -> 3/4 of Wb left as poison). --------
__global__ __launch_bounds__(256) void k_nfwb(const float* __restrict__ nf,
                                              _Float16* __restrict__ nfh,
                                              const float* __restrict__ W,
                                              _Float16* __restrict__ Wb,
                                              int* __restrict__ gcur) {
  const int gid = blockIdx.x * 256 + threadIdx.x;
  if (gid < NBUK) gcur[gid] = gid * BCAP;
  if (gid < N_NODES * 16) {
    const int i = gid * 4;
    const f32x4 v = *reinterpret_cast<const f32x4*>(nf + i);
    f16x4 h;
    #pragma unroll
    for (int j = 0; j < 4; ++j) h[j] = (_Float16)v[j];
    *reinterpret_cast<f16x4*>(nfh + i) = h;
  } else {
    const int idx = gid - N_NODES * 16;
    if (idx < WB_ELEMS) {
      const int i  = idx & 7;
      const int l  = (idx >> 3) & 63;
      const int n  = (idx >> 9) & 3;
      const int kc = idx >> 11;
      const int k  = kc * 32 + ((l >> 4) << 3) + i;
      const int o  = n * 16 + (l & 15);
      Wb[idx] = (_Float16)W[o * K_DIM + k];
    }
  }
}

// -------- K_seed (fallback path only) --------
__global__ void k_seed(int* __restrict__ gcur) {
  int b = blockIdx.x * blockDim.x + threadIdx.x;
  if (b < NBUK) gcur[b] = b * BCAP;
}

// -------- K3a: bin edges into fixed-capacity 256-row buckets --------
__global__ __launch_bounds__(256) void k_bin(const int* __restrict__ rows,
                                             const int* __restrict__ cols,
                                             int* __restrict__ gcur,
                                             int* __restrict__ binArr) {
  __shared__ int hist[NBUK];
  __shared__ int base_s[NBUK];
  const int t  = threadIdx.x;
  const int e0 = blockIdx.x * EPB;
  for (int b = t; b < NBUK; b += 256) hist[b] = 0;
  __syncthreads();
  for (int i = 0; i < EPB / 256; ++i) {
    const int e = e0 + i * 256 + t;
    if (e < NNZ_E) atomicAdd(&hist[rows[e] >> 8], 1);
  }
  __syncthreads();
  for (int b = t; b < NBUK; b += 256) {
    const int h = hist[b];
    base_s[b] = h ? atomicAdd(&gcur[b], h) : 0;
    hist[b] = 0;
  }
  __syncthreads();
  for (int i = 0; i < EPB / 256; ++i) {
    const int e = e0 + i * 256 + t;
    if (e < NNZ_E) {
      const int r = rows[e], c = cols[e], b = r >> 8;
      const int p = atomicAdd(&hist[b], 1);
      const int slot = base_s[b] + p;
      if (slot < (b + 1) * BCAP)                    // statistical guard
        binArr[slot] = ((r & 255) << 24) | c;       // col < 2^17 fits 24 bits
    }
  }
}

// -------- K_sortbucket: per bucket: hist -> cnt, scan -> row_start,
//          in-place scatter -> bucket-strided byte-offset CSR, log10 partial --------
__global__ __launch_bounds__(256) void k_sortbucket(int* __restrict__ bincsr,
                                                    const int* __restrict__ gcur,
                                                    int* __restrict__ cnt,
                                                    int* __restrict__ row_start,
                                                    float* __restrict__ partial) {
  __shared__ int se[BCAP];       // 20 KB edge stage
  __shared__ int hist[256];
  __shared__ int curs[256];
  __shared__ int sd[256];
  __shared__ float wsum[4];
  const int b = blockIdx.x, t = threadIdx.x;
  const int s0  = b * BCAP;
  const int len = min(gcur[b] - s0, BCAP);
  for (int i = t; i < len; i += 256) se[i] = bincsr[s0 + i];
  hist[t] = 0;
  __syncthreads();
  for (int i = t; i < len; i += 256)
    atomicAdd(&hist[((unsigned)se[i]) >> 24], 1);
  __syncthreads();
  const int h = hist[t];
  const int r = (b << 8) + t;
  sd[t] = h;
  __syncthreads();
  #pragma unroll
  for (int off = 1; off < 256; off <<= 1) {
    int add = (t >= off) ? sd[t - off] : 0;
    __syncthreads();
    sd[t] += add;
    __syncthreads();
  }
  const int excl = sd[t] - h;
  curs[t] = excl;
  if (r < M_ROWS) {
    cnt[r] = h;
    row_start[r] = s0 + excl;
  }
  float ls = (r < M_ROWS) ? log10f((float)h + 2.0f) : 0.f;
  #pragma unroll
  for (int off = 32; off > 0; off >>= 1) ls += __shfl_xor(ls, off);
  if ((t & 63) == 0) wsum[t >> 6] = ls;
  __syncthreads();
  if (t == 0) partial[b] = wsum[0] + wsum[1] + wsum[2] + wsum[3];
  for (int i = t; i < len; i += 256) {
    const int e  = se[i];
    const int rl = (int)(((unsigned)e) >> 24);
    const int p  = atomicAdd(&curs[rl], 1);
    bincsr[s0 + p] = (e & 0x00FFFFFF) << 7;        // byte offset into f16 table
  }
}

// -------- K_delta: mean(log10(deg+2)) from 391 bucket partials --------
__global__ void k_delta(const float* __restrict__ partial, float* __restrict__ delta) {
  __shared__ float sd[256];
  const int t = threadIdx.x;
  float s = 0.f;
  for (int i = t; i < NBUK; i += 256) s += partial[i];
  sd[t] = s;
  __syncthreads();
  for (int off = 128; off > 0; off >>= 1) {
    if (t < off) sd[t] += sd[t + off];
    __syncthreads();
  }
  if (t == 0) delta[0] = sd[0] / (float)M_ROWS;
}

// -------- K5: fused stats + MFMA, grid-stride 2 tiles/block --------
template <bool F16NF>
__global__ __launch_bounds__(256) void k_main(
    const float* __restrict__ nf32, const _Float16* __restrict__ nfh,
    const int* __restrict__ csr, const int* __restrict__ rs,
    const int* __restrict__ cnt, const float* __restrict__ delta_p,
    const _Float16* __restrict__ Wb, const float* __restrict__ bias,
    float* __restrict__ out)
{
  __shared__ _Float16 xs[32][264];
  __shared__ float s_s[32];

  const int tid  = threadIdx.x;
  const int w    = tid >> 6;
  const int lane = tid & 63;
  const int g    = lane >> 4;        // group (row) within wave
  const int q    = lane & 15;        // lane within group
  const int h    = (lane >> 3) & 1;  // edge parity handled by this lane
  const int d    = lane & 7;         // dim block (8 dims)
  const float delta = delta_p[0];
  const int d16  = d * 16;           // byte offset of dim block in f16 row

  auto ld16 = [&](int off) -> f16x8 {
    if constexpr (F16NF) {
      return *reinterpret_cast<const f16x8*>((const char*)nfh + off + d16);
    } else {
      const char* p = (const char*)nf32 + (size_t)off * 2 + d * 32;
      const f32x4 a = *reinterpret_cast<const f32x4*>(p);
      const f32x4 c = *reinterpret_cast<const f32x4*>(p + 16);
      f16x8 x;
      #pragma unroll
      for (int j = 0; j < 4; ++j) { x[j] = (_Float16)a[j]; x[4 + j] = (_Float16)c[j]; }
      return x;
    }
  };

  auto xor8 = [&](f16x8 v) -> f16x8 {
    union { f16x8 hh; int ii[4]; } u;
    u.hh = v;
    #pragma unroll
    for (int k = 0; k < 4; ++k) u.ii[k] = __shfl_xor(u.ii[k], 8);
    return u.hh;
  };

  for (int tile = blockIdx.x; tile < NTILE; tile += GMAIN) {
    const int r0 = tile * 32;

    #pragma unroll
    for (int pass = 0; pass < 2; ++pass) {
      const int rl  = w * 8 + pass * 4 + g;
      const int r   = r0 + rl;
      const int js  = rs[r];
      const int len = cnt[r];            // true degree (>=1 by construction)
      const int full8 = len & ~7;        // edges covered by mask-free iterations
      const int tailn = len - full8;     // 0..7 edges left for the masked tail
      int mfull = full8, mtail = tailn;
      mfull = max(mfull, __shfl_xor(mfull, 16));
      mfull = max(mfull, __shfl_xor(mfull, 32));
      mtail = max(mtail, __shfl_xor(mtail, 16));
      mtail = max(mtail, __shfl_xor(mtail, 32));

      f16x8 hsum = {}; f16x8 hsq = {}; f16x8 hmx = {};
      f16x8 hmn = {(_Float16)INFINITY, (_Float16)INFINITY, (_Float16)INFINITY,
                   (_Float16)INFINITY, (_Float16)INFINITY, (_Float16)INFINITY,
                   (_Float16)INFINITY, (_Float16)INFINITY};

      const int jb = js + h;             // lane's index stream: edges h, h+2, ...

      // ---- mask-free full iterations (indices provably < len) ----
      for (int t = 0; t < mfull; t += 8) {
        if (t < full8) {                 // group-uniform
          const int i0 = csr[jb + t + 0];
          const int i1 = csr[jb + t + 2];
          const int i2 = csr[jb + t + 4];
          const int i3 = csr[jb + t + 6];
          const f16x8 x0 = ld16(i0), x1 = ld16(i1), x2 = ld16(i2), x3 = ld16(i3);
          hmx = __builtin_elementwise_max(hmx, x0);
          hmn = __builtin_elementwise_min(hmn, x0);
          hsum += x0; hsq += x0 * x0;
          hmx = __builtin_elementwise_max(hmx, x1);
          hmn = __builtin_elementwise_min(hmn, x1);
          hsum += x1; hsq += x1 * x1;
          hmx = __builtin_elementwise_max(hmx, x2);
          hmn = __builtin_elementwise_min(hmn, x2);
          hsum += x2; hsq += x2 * x2;
          hmx = __builtin_elementwise_max(hmx, x3);
          hmn = __builtin_elementwise_min(hmn, x3);
          hsum += x3; hsq += x3 * x3;
        }
      }

      // ---- clamped + masked tail (any-row-in-wave gate; idempotent rows safe) ----
      if (mtail > 0) {
        const int last = js + len - 1;
        const int e0 = full8 + 0 + h, e1 = full8 + 2 + h;
        const int e2 = full8 + 4 + h, e3 = full8 + 6 + h;
        const int i0 = csr[min(jb + full8 + 0, last)];
        const int i1 = csr[min(jb + full8 + 2, last)];
        const int i2 = csr[min(jb + full8 + 4, last)];
        const int i3 = csr[min(jb + full8 + 6, last)];
        const f16x8 x0 = ld16(i0), x1 = ld16(i1), x2 = ld16(i2), x3 = ld16(i3);
        const f16x8 z = {};
        const f16x8 m0 = (e0 < len) ? x0 : z;
        const f16x8 m1 = (e1 < len) ? x1 : z;
        const f16x8 m2 = (e2 < len) ? x2 : z;
        const f16x8 m3 = (e3 < len) ? x3 : z;
        hmx = __builtin_elementwise_max(hmx, x0);
        hmn = __builtin_elementwise_min(hmn, x0);
        hsum += m0; hsq += m0 * x0;
        hmx = __builtin_elementwise_max(hmx, x1);
        hmn = __builtin_elementwise_min(hmn, x1);
        hsum += m1; hsq += m1 * x1;
        hmx = __builtin_elementwise_max(hmx, x2);
        hmn = __builtin_elementwise_min(hmn, x2);
        hsum += m2; hsq += m2 * x2;
        hmx = __builtin_elementwise_max(hmx, x3);
        hmn = __builtin_elementwise_min(hmn, x3);
        hsum += m3; hsq += m3 * x3;
      }

      // ---- combine even/odd halves (lane <-> lane^8) ----
      hsum += xor8(hsum);
      hsq  += xor8(hsq);
      hmx = __builtin_elementwise_max(hmx, xor8(hmx));
      hmn = __builtin_elementwise_min(hmn, xor8(hmn));

      const float dg  = (float)len;
      const float inv = 1.0f / fmaxf(dg, 1.0f);
      f16x8 hmean, hstd;
      #pragma unroll
      for (int i = 0; i < 8; ++i) {
        const float mean = (float)hsum[i] * inv;
        const float sqm  = (float)hsq[i] * inv;
        const float var  = fmaxf(sqm - mean * mean, 0.f);
        hmean[i] = (_Float16)mean;
        hstd[i]  = (_Float16)sqrtf(var);
      }
      if (h == 0) {                      // lanes q<8 write; halves identical
        *reinterpret_cast<f16x8*>(&xs[rl][0 * 64 + d * 8]) = hmean;
        *reinterpret_cast<f16x8*>(&xs[rl][1 * 64 + d * 8]) = hmx;
        *reinterpret_cast<f16x8*>(&xs[rl][2 * 64 + d * 8]) = hmn;
        *reinterpret_cast<f16x8*>(&xs[rl][3 * 64 + d * 8]) = hstd;
        if (q == 0) s_s[rl] = log10f(dg + 2.0f) / delta;
      }
    }
    __syncthreads();

    // ---- phase 2: wave w -> cols w*16..+16, row tiles 0..15 / 16..31 ----
    f32x4 acc0 = {0.f, 0.f, 0.f, 0.f}, acc1 = {0.f, 0.f, 0.f, 0.f};
    const int khi = lane >> 4;
    const float sA = s_s[q];
    const float sB = s_s[16 + q];
    const f16x8 sA8  = (f16x8)(_Float16)sA;
    const f16x8 isA8 = (f16x8)(_Float16)(1.0f / sA);
    const f16x8 sB8  = (f16x8)(_Float16)sB;
    const f16x8 isB8 = (f16x8)(_Float16)(1.0f / sB);

    #pragma unroll
    for (int kc = 0; kc < NCHUNK; ++kc) {
      const int kb = kc >> 1;
      const int a  = kb / 3;
      const int tt = kb - 3 * a;
      const int off = a * 64 + ((kc & 1) << 5) + (khi << 3);
      f16x8 a0 = *reinterpret_cast<const f16x8*>(&xs[q][off]);
      f16x8 a1 = *reinterpret_cast<const f16x8*>(&xs[16 + q][off]);
      if (tt == 1) { a0 = a0 * sA8;  a1 = a1 * sB8; }
      if (tt == 2) { a0 = a0 * isA8; a1 = a1 * isB8; }
      const f16x8 bf = *reinterpret_cast<const f16x8*>(Wb + ((size_t)(kc * 4 + w) * 64 + lane) * 8);
      acc0 = __builtin_amdgcn_mfma_f32_16x16x32_f16(a0, bf, acc0, 0, 0, 0);
      acc1 = __builtin_amdgcn_mfma_f32_16x16x32_f16(a1, bf, acc1, 0, 0, 0);
    }

    const int col = w * 16 + q;
    const float bv = bias[col];
    #pragma unroll
    for (int i = 0; i < 4; ++i) {
      const int rr = khi * 4 + i;
      float v = acc0[i] + bv;
      v = (v >= 0.f) ? v : NEG_SLOPE * v;
      out[(size_t)(r0 + rr) * 64 + col] = v;
      float u = acc1[i] + bv;
      u = (u >= 0.f) ? u : NEG_SLOPE * u;
      out[(size_t)(r0 + 16 + rr) * 64 + col] = u;
    }
    __syncthreads();                   // protect xs/s_s before next tile
  }
}

extern "C" void kernel_launch(void* const* d_in, const int* in_sizes, int n_in,
                              void* d_out, int out_size, void* d_ws, size_t ws_size,
                              hipStream_t stream) {
  const int*   rows = (const int*)d_in[0];
  const int*   cols = (const int*)d_in[1];
  const float* nf   = (const float*)d_in[3];
  const float* W    = (const float*)d_in[4];
  const float* bias = (const float*)d_in[5];
  float* out = (float*)d_out;

  char* ws = (char*)d_ws;
  int*      cnt       = (int*)(ws + OFF_CNT);
  int*      row_start = (int*)(ws + OFF_RS);
  float*    partial   = (float*)(ws + OFF_PART);
  float*    delta     = (float*)(ws + OFF_DELTA);
  int*      gcur      = (int*)(ws + OFF_GCUR);
  int*      bincsr    = (int*)(ws + OFF_BINCSR);
  _Float16* Wb        = (_Float16*)(ws + OFF_WB);
  _Float16* nfh       = (_Float16*)(ws + OFF_NFH);

  const bool f16path = (ws_size >= WS_NEEDED);

  if (f16path) {
    k_nfwb<<<NFWB_BLOCKS, 256, 0, stream>>>(nf, nfh, W, Wb, gcur);
  } else {
    k_wb<<<192, 256, 0, stream>>>(W, Wb);
    k_seed<<<2, 256, 0, stream>>>(gcur);
  }
  k_bin<<<(NNZ_E + EPB - 1) / EPB, 256, 0, stream>>>(rows, cols, gcur, bincsr);
  k_sortbucket<<<NBUK, 256, 0, stream>>>(bincsr, gcur, cnt, row_start, partial);
  k_delta<<<1, 256, 0, stream>>>(partial, delta);
  if (f16path)
    k_main<true><<<GMAIN, 256, 0, stream>>>(nf, nfh, bincsr, row_start, cnt, delta, Wb, bias, out);
  else
    k_main<false><<<GMAIN, 256, 0, stream>>>(nf, nfh, bincsr, row_start, cnt, delta, Wb, bias, out);
}

// Round 15
// 105.001 us; speedup vs baseline: 1.2693x; 1.2693x over previous
//
#include <hip/hip_runtime.h>
#include <cstdint>

#define M_ROWS   100000
#define N_NODES  100000
#define NNZ_E    1600000
#define K_DIM    768
#define NCHUNK   24
#define NEG_SLOPE 0.2f
#define NBUK     391           // ceil(M/256) buckets of 256 rows
#define BCAP     5120          // bucket capacity (mean 4096 + 16 sigma)
#define EPB      8192          // edges per k_bin block
#define WB_ELEMS (NCHUNK * 4 * 64 * 8)   // 49152
#define NFWB_BLOCKS ((N_NODES * 16 + WB_ELEMS + 255) / 256)  // 6442

using f32x4 = __attribute__((ext_vector_type(4))) float;
using f16x8 = __attribute__((ext_vector_type(8))) _Float16;
using f16x4 = __attribute__((ext_vector_type(4))) _Float16;

// ---------------- workspace layout (bytes) ----------------
#define OFF_CNT    0u          // int[100352] true counts (k_sortbucket)
#define OFF_RS     401408u     // int[100352] bucket-strided row starts
#define OFF_PART   802816u     // float[512]
#define OFF_DELTA  804864u     // float (pad 256)
#define OFF_GCUR   805120u     // int[512]
#define OFF_BINCSR 807168u     // int[NBUK*BCAP]: k_bin packed edges, then in-place CSR
#define OFF_WB     8814848u    // _Float16[49152]
#define OFF_NFH    8913152u    // _Float16[N*64] = 12.8 MB (128B-aligned rows)
#define WS_NEEDED  21713152u

// -------- K0 (fallback path only): pack W into f16 B-fragments --------
__global__ void k_wb(const float* __restrict__ W, _Float16* __restrict__ Wb) {
  int idx = blockIdx.x * blockDim.x + threadIdx.x;
  if (idx < WB_ELEMS) {
    int i  = idx & 7;
    int l  = (idx >> 3) & 63;
    int n  = (idx >> 9) & 3;
    int kc = idx >> 11;
    int k  = kc * 32 + ((l >> 4) << 3) + i;
    int o  = n * 16 + (l & 15);
    Wb[idx] = (_Float16)W[o * K_DIM + k];
  }
}

// -------- K0b (f16 path): nf->f16 + Wb pack + gcur seed, one kernel.
//          Grid = 6442 blocks: 1,600,000 nf threads + 49,152 Wb threads. --------
__global__ __launch_bounds__(256) void k_nfwb(const float* __restrict__ nf,
                                              _Float16* __restrict__ nfh,
                                              const float* __restrict__ W,
                                              _Float16* __restrict__ Wb,
                                              int* __restrict__ gcur) {
  const int gid = blockIdx.x * 256 + threadIdx.x;
  if (gid < NBUK) gcur[gid] = gid * BCAP;
  if (gid < N_NODES * 16) {
    const int i = gid * 4;
    const f32x4 v = *reinterpret_cast<const f32x4*>(nf + i);
    f16x4 h;
    #pragma unroll
    for (int j = 0; j < 4; ++j) h[j] = (_Float16)v[j];
    *reinterpret_cast<f16x4*>(nfh + i) = h;
  } else {
    const int idx = gid - N_NODES * 16;
    if (idx < WB_ELEMS) {
      const int i  = idx & 7;
      const int l  = (idx >> 3) & 63;
      const int n  = (idx >> 9) & 3;
      const int kc = idx >> 11;
      const int k  = kc * 32 + ((l >> 4) << 3) + i;
      const int o  = n * 16 + (l & 15);
      Wb[idx] = (_Float16)W[o * K_DIM + k];
    }
  }
}

// -------- K_seed (fallback path only) --------
__global__ void k_seed(int* __restrict__ gcur) {
  int b = blockIdx.x * blockDim.x + threadIdx.x;
  if (b < NBUK) gcur[b] = b * BCAP;
}

// -------- K3a: bin edges into fixed-capacity 256-row buckets --------
__global__ __launch_bounds__(256) void k_bin(const int* __restrict__ rows,
                                             const int* __restrict__ cols,
                                             int* __restrict__ gcur,
                                             int* __restrict__ binArr) {
  __shared__ int hist[NBUK];
  __shared__ int base_s[NBUK];
  const int t  = threadIdx.x;
  const int e0 = blockIdx.x * EPB;
  for (int b = t; b < NBUK; b += 256) hist[b] = 0;
  __syncthreads();
  for (int i = 0; i < EPB / 256; ++i) {
    const int e = e0 + i * 256 + t;
    if (e < NNZ_E) atomicAdd(&hist[rows[e] >> 8], 1);
  }
  __syncthreads();
  for (int b = t; b < NBUK; b += 256) {
    const int h = hist[b];
    base_s[b] = h ? atomicAdd(&gcur[b], h) : 0;
    hist[b] = 0;
  }
  __syncthreads();
  for (int i = 0; i < EPB / 256; ++i) {
    const int e = e0 + i * 256 + t;
    if (e < NNZ_E) {
      const int r = rows[e], c = cols[e], b = r >> 8;
      const int p = atomicAdd(&hist[b], 1);
      const int slot = base_s[b] + p;
      if (slot < (b + 1) * BCAP)                    // statistical guard
        binArr[slot] = ((r & 255) << 24) | c;       // col < 2^17 fits 24 bits
    }
  }
}

// -------- K_sortbucket: per bucket: hist -> cnt, scan -> row_start,
//          in-place scatter -> bucket-strided byte-offset CSR, log10 partial --------
__global__ __launch_bounds__(256) void k_sortbucket(int* __restrict__ bincsr,
                                                    const int* __restrict__ gcur,
                                                    int* __restrict__ cnt,
                                                    int* __restrict__ row_start,
                                                    float* __restrict__ partial) {
  __shared__ int se[BCAP];       // 20 KB edge stage
  __shared__ int hist[256];
  __shared__ int curs[256];
  __shared__ int sd[256];
  __shared__ float wsum[4];
  const int b = blockIdx.x, t = threadIdx.x;
  const int s0  = b * BCAP;
  const int len = min(gcur[b] - s0, BCAP);
  for (int i = t; i < len; i += 256) se[i] = bincsr[s0 + i];
  hist[t] = 0;
  __syncthreads();
  for (int i = t; i < len; i += 256)
    atomicAdd(&hist[((unsigned)se[i]) >> 24], 1);
  __syncthreads();
  const int h = hist[t];
  const int r = (b << 8) + t;
  sd[t] = h;
  __syncthreads();
  #pragma unroll
  for (int off = 1; off < 256; off <<= 1) {
    int add = (t >= off) ? sd[t - off] : 0;
    __syncthreads();
    sd[t] += add;
    __syncthreads();
  }
  const int excl = sd[t] - h;
  curs[t] = excl;
  if (r < M_ROWS) {
    cnt[r] = h;
    row_start[r] = s0 + excl;
  }
  float ls = (r < M_ROWS) ? log10f((float)h + 2.0f) : 0.f;
  #pragma unroll
  for (int off = 32; off > 0; off >>= 1) ls += __shfl_xor(ls, off);
  if ((t & 63) == 0) wsum[t >> 6] = ls;
  __syncthreads();
  if (t == 0) partial[b] = wsum[0] + wsum[1] + wsum[2] + wsum[3];
  for (int i = t; i < len; i += 256) {
    const int e  = se[i];
    const int rl = (int)(((unsigned)e) >> 24);
    const int p  = atomicAdd(&curs[rl], 1);
    bincsr[s0 + p] = (e & 0x00FFFFFF) << 7;        // byte offset into f16 table
  }
}

// -------- K_delta: mean(log10(deg+2)) from 391 bucket partials --------
__global__ void k_delta(const float* __restrict__ partial, float* __restrict__ delta) {
  __shared__ float sd[256];
  const int t = threadIdx.x;
  float s = 0.f;
  for (int i = t; i < NBUK; i += 256) s += partial[i];
  sd[t] = s;
  __syncthreads();
  for (int off = 128; off > 0; off >>= 1) {
    if (t < off) sd[t] += sd[t + off];
    __syncthreads();
  }
  if (t == 0) delta[0] = sd[0] / (float)M_ROWS;
}

// -------- K5: fused stats (2-edge/16B-lane, tail-split) + MFMA epilogue.
//          ONE tile per block (r12 structure): VGPR 44, ~40% occupancy —
//          grid-stride 2-tiles/block (r14) doubled VGPR to 92 and cost +27 µs. --------
template <bool F16NF>
__global__ __launch_bounds__(256) void k_main(
    const float* __restrict__ nf32, const _Float16* __restrict__ nfh,
    const int* __restrict__ csr, const int* __restrict__ rs,
    const int* __restrict__ cnt, const float* __restrict__ delta_p,
    const _Float16* __restrict__ Wb, const float* __restrict__ bias,
    float* __restrict__ out)
{
  __shared__ _Float16 xs[32][264];
  __shared__ float s_s[32];

  const int tid  = threadIdx.x;
  const int w    = tid >> 6;
  const int lane = tid & 63;
  const int g    = lane >> 4;        // group (row) within wave
  const int q    = lane & 15;        // lane within group
  const int h    = (lane >> 3) & 1;  // edge parity handled by this lane
  const int d    = lane & 7;         // dim block (8 dims)
  const int r0   = blockIdx.x * 32;
  const float delta = delta_p[0];
  const int d16  = d * 16;           // byte offset of dim block in f16 row

  auto ld16 = [&](int off) -> f16x8 {
    if constexpr (F16NF) {
      return *reinterpret_cast<const f16x8*>((const char*)nfh + off + d16);
    } else {
      const char* p = (const char*)nf32 + (size_t)off * 2 + d * 32;
      const f32x4 a = *reinterpret_cast<const f32x4*>(p);
      const f32x4 c = *reinterpret_cast<const f32x4*>(p + 16);
      f16x8 x;
      #pragma unroll
      for (int j = 0; j < 4; ++j) { x[j] = (_Float16)a[j]; x[4 + j] = (_Float16)c[j]; }
      return x;
    }
  };

  auto xor8 = [&](f16x8 v) -> f16x8 {
    union { f16x8 hh; int ii[4]; } u;
    u.hh = v;
    #pragma unroll
    for (int k = 0; k < 4; ++k) u.ii[k] = __shfl_xor(u.ii[k], 8);
    return u.hh;
  };

  #pragma unroll
  for (int pass = 0; pass < 2; ++pass) {
    const int rl  = w * 8 + pass * 4 + g;
    const int r   = r0 + rl;
    const int js  = rs[r];
    const int len = cnt[r];            // true degree (>=1 by construction)
    const int full8 = len & ~7;        // edges covered by mask-free iterations
    const int tailn = len - full8;     // 0..7 edges left for the masked tail
    int mfull = full8, mtail = tailn;
    mfull = max(mfull, __shfl_xor(mfull, 16));
    mfull = max(mfull, __shfl_xor(mfull, 32));
    mtail = max(mtail, __shfl_xor(mtail, 16));
    mtail = max(mtail, __shfl_xor(mtail, 32));

    f16x8 hsum = {}; f16x8 hsq = {}; f16x8 hmx = {};
    f16x8 hmn = {(_Float16)INFINITY, (_Float16)INFINITY, (_Float16)INFINITY,
                 (_Float16)INFINITY, (_Float16)INFINITY, (_Float16)INFINITY,
                 (_Float16)INFINITY, (_Float16)INFINITY};

    const int jb = js + h;             // lane's index stream: edges h, h+2, ...

    // ---- mask-free full iterations (indices provably < len) ----
    for (int t = 0; t < mfull; t += 8) {
      if (t < full8) {                 // group-uniform
        const int i0 = csr[jb + t + 0];
        const int i1 = csr[jb + t + 2];
        const int i2 = csr[jb + t + 4];
        const int i3 = csr[jb + t + 6];
        const f16x8 x0 = ld16(i0), x1 = ld16(i1), x2 = ld16(i2), x3 = ld16(i3);
        hmx = __builtin_elementwise_max(hmx, x0);
        hmn = __builtin_elementwise_min(hmn, x0);
        hsum += x0; hsq += x0 * x0;
        hmx = __builtin_elementwise_max(hmx, x1);
        hmn = __builtin_elementwise_min(hmn, x1);
        hsum += x1; hsq += x1 * x1;
        hmx = __builtin_elementwise_max(hmx, x2);
        hmn = __builtin_elementwise_min(hmn, x2);
        hsum += x2; hsq += x2 * x2;
        hmx = __builtin_elementwise_max(hmx, x3);
        hmn = __builtin_elementwise_min(hmn, x3);
        hsum += x3; hsq += x3 * x3;
      }
    }

    // ---- clamped + masked tail (any-row-in-wave gate; idempotent rows safe) ----
    if (mtail > 0) {
      const int last = js + len - 1;
      const int e0 = full8 + 0 + h, e1 = full8 + 2 + h;
      const int e2 = full8 + 4 + h, e3 = full8 + 6 + h;
      const int i0 = csr[min(jb + full8 + 0, last)];
      const int i1 = csr[min(jb + full8 + 2, last)];
      const int i2 = csr[min(jb + full8 + 4, last)];
      const int i3 = csr[min(jb + full8 + 6, last)];
      const f16x8 x0 = ld16(i0), x1 = ld16(i1), x2 = ld16(i2), x3 = ld16(i3);
      const f16x8 z = {};
      const f16x8 m0 = (e0 < len) ? x0 : z;
      const f16x8 m1 = (e1 < len) ? x1 : z;
      const f16x8 m2 = (e2 < len) ? x2 : z;
      const f16x8 m3 = (e3 < len) ? x3 : z;
      hmx = __builtin_elementwise_max(hmx, x0);
      hmn = __builtin_elementwise_min(hmn, x0);
      hsum += m0; hsq += m0 * x0;
      hmx = __builtin_elementwise_max(hmx, x1);
      hmn = __builtin_elementwise_min(hmn, x1);
      hsum += m1; hsq += m1 * x1;
      hmx = __builtin_elementwise_max(hmx, x2);
      hmn = __builtin_elementwise_min(hmn, x2);
      hsum += m2; hsq += m2 * x2;
      hmx = __builtin_elementwise_max(hmx, x3);
      hmn = __builtin_elementwise_min(hmn, x3);
      hsum += m3; hsq += m3 * x3;
    }

    // ---- combine even/odd halves (lane <-> lane^8) ----
    hsum += xor8(hsum);
    hsq  += xor8(hsq);
    hmx = __builtin_elementwise_max(hmx, xor8(hmx));
    hmn = __builtin_elementwise_min(hmn, xor8(hmn));

    const float dg  = (float)len;
    const float inv = 1.0f / fmaxf(dg, 1.0f);
    f16x8 hmean, hstd;
    #pragma unroll
    for (int i = 0; i < 8; ++i) {
      const float mean = (float)hsum[i] * inv;
      const float sqm  = (float)hsq[i] * inv;
      const float var  = fmaxf(sqm - mean * mean, 0.f);
      hmean[i] = (_Float16)mean;
      hstd[i]  = (_Float16)sqrtf(var);
    }
    if (h == 0) {                      // lanes q<8 write; halves identical
      *reinterpret_cast<f16x8*>(&xs[rl][0 * 64 + d * 8]) = hmean;
      *reinterpret_cast<f16x8*>(&xs[rl][1 * 64 + d * 8]) = hmx;
      *reinterpret_cast<f16x8*>(&xs[rl][2 * 64 + d * 8]) = hmn;
      *reinterpret_cast<f16x8*>(&xs[rl][3 * 64 + d * 8]) = hstd;
      if (q == 0) s_s[rl] = log10f(dg + 2.0f) / delta;
    }
  }
  __syncthreads();

  // ---- phase 2: wave w -> cols w*16..+16, row tiles 0..15 / 16..31 ----
  f32x4 acc0 = {0.f, 0.f, 0.f, 0.f}, acc1 = {0.f, 0.f, 0.f, 0.f};
  const int khi = lane >> 4;
  const float sA = s_s[q];
  const float sB = s_s[16 + q];
  const f16x8 sA8  = (f16x8)(_Float16)sA;
  const f16x8 isA8 = (f16x8)(_Float16)(1.0f / sA);
  const f16x8 sB8  = (f16x8)(_Float16)sB;
  const f16x8 isB8 = (f16x8)(_Float16)(1.0f / sB);

  #pragma unroll
  for (int kc = 0; kc < NCHUNK; ++kc) {
    const int kb = kc >> 1;
    const int a  = kb / 3;
    const int tt = kb - 3 * a;
    const int off = a * 64 + ((kc & 1) << 5) + (khi << 3);
    f16x8 a0 = *reinterpret_cast<const f16x8*>(&xs[q][off]);
    f16x8 a1 = *reinterpret_cast<const f16x8*>(&xs[16 + q][off]);
    if (tt == 1) { a0 = a0 * sA8;  a1 = a1 * sB8; }
    if (tt == 2) { a0 = a0 * isA8; a1 = a1 * isB8; }
    const f16x8 bf = *reinterpret_cast<const f16x8*>(Wb + ((size_t)(kc * 4 + w) * 64 + lane) * 8);
    acc0 = __builtin_amdgcn_mfma_f32_16x16x32_f16(a0, bf, acc0, 0, 0, 0);
    acc1 = __builtin_amdgcn_mfma_f32_16x16x32_f16(a1, bf, acc1, 0, 0, 0);
  }

  const int col = w * 16 + q;
  const float bv = bias[col];
  #pragma unroll
  for (int i = 0; i < 4; ++i) {
    const int rr = khi * 4 + i;
    float v = acc0[i] + bv;
    v = (v >= 0.f) ? v : NEG_SLOPE * v;
    out[(size_t)(r0 + rr) * 64 + col] = v;
    float u = acc1[i] + bv;
    u = (u >= 0.f) ? u : NEG_SLOPE * u;
    out[(size_t)(r0 + 16 + rr) * 64 + col] = u;
  }
}

extern "C" void kernel_launch(void* const* d_in, const int* in_sizes, int n_in,
                              void* d_out, int out_size, void* d_ws, size_t ws_size,
                              hipStream_t stream) {
  const int*   rows = (const int*)d_in[0];
  const int*   cols = (const int*)d_in[1];
  const float* nf   = (const float*)d_in[3];
  const float* W    = (const float*)d_in[4];
  const float* bias = (const float*)d_in[5];
  float* out = (float*)d_out;

  char* ws = (char*)d_ws;
  int*      cnt       = (int*)(ws + OFF_CNT);
  int*      row_start = (int*)(ws + OFF_RS);
  float*    partial   = (float*)(ws + OFF_PART);
  float*    delta     = (float*)(ws + OFF_DELTA);
  int*      gcur      = (int*)(ws + OFF_GCUR);
  int*      bincsr    = (int*)(ws + OFF_BINCSR);
  _Float16* Wb        = (_Float16*)(ws + OFF_WB);
  _Float16* nfh       = (_Float16*)(ws + OFF_NFH);

  const bool f16path = (ws_size >= WS_NEEDED);

  if (f16path) {
    k_nfwb<<<NFWB_BLOCKS, 256, 0, stream>>>(nf, nfh, W, Wb, gcur);
  } else {
    k_wb<<<192, 256, 0, stream>>>(W, Wb);
    k_seed<<<2, 256, 0, stream>>>(gcur);
  }
  k_bin<<<(NNZ_E + EPB - 1) / EPB, 256, 0, stream>>>(rows, cols, gcur, bincsr);
  k_sortbucket<<<NBUK, 256, 0, stream>>>(bincsr, gcur, cnt, row_start, partial);
  k_delta<<<1, 256, 0, stream>>>(partial, delta);
  if (f16path)
    k_main<true><<<M_ROWS / 32, 256, 0, stream>>>(nf, nfh, bincsr, row_start, cnt, delta, Wb, bias, out);
  else
    k_main<false><<<M_ROWS / 32, 256, 0, stream>>>(nf, nfh, bincsr, row_start, cnt, delta, Wb, bias, out);
}

// Round 16
// 93.724 us; speedup vs baseline: 1.4221x; 1.1203x over previous
//
#include <hip/hip_runtime.h>
#include <cstdint>

#define M_ROWS   100000
#define N_NODES  100000
#define NNZ_E    1600000
#define K_DIM    768
#define NCHUNK   24
#define NEG_SLOPE 0.2f
#define NBUK     391           // ceil(M/256) buckets of 256 rows
#define BCAP     5120          // bucket capacity (mean 4096 + 16 sigma)
#define EPB      8192          // edges per bin block
#define BIN_BLOCKS ((NNZ_E + EPB - 1) / EPB)        // 196
#define WB_ELEMS (NCHUNK * 4 * 64 * 8)              // 49152
#define NF_THREADS (N_NODES * 16)                   // 1,600,000

using f32x4 = __attribute__((ext_vector_type(4))) float;
using f16x8 = __attribute__((ext_vector_type(8))) _Float16;
using f16x4 = __attribute__((ext_vector_type(4))) _Float16;

// ---------------- workspace layout (bytes) ----------------
#define OFF_CNT    0u          // int[100352] true counts (k_sortbucket)
#define OFF_RS     401408u     // int[100352] bucket-strided row starts
#define OFF_PART   802816u     // float[512]
#define OFF_GCUR   805120u     // int[512] ZERO-BASED cursors (memset 0 each call)
#define OFF_BINCSR 807168u     // int[NBUK*BCAP]: packed edges, then in-place CSR
#define OFF_WB     8814848u    // _Float16[49152]
#define OFF_NFH    8913152u    // _Float16[N*64] = 12.8 MB (128B-aligned rows)
#define WS_NEEDED  21713152u

// -------- K_prep2: fused {bin (int4 loads)} + {nf->f16, Wb pack} --------
// gcur must be zeroed before launch (zero-based cursors).
template <bool DO_NF>
__global__ __launch_bounds__(256) void k_prep2(const int* __restrict__ rows,
                                               const int* __restrict__ cols,
                                               int* __restrict__ gcur,
                                               int* __restrict__ binArr,
                                               const float* __restrict__ nf,
                                               _Float16* __restrict__ nfh,
                                               const float* __restrict__ W,
                                               _Float16* __restrict__ Wb) {
  __shared__ int hist[NBUK];
  __shared__ int base_s[NBUK];
  const int t = threadIdx.x;

  if (blockIdx.x < BIN_BLOCKS) {
    // ---------------- bin branch ----------------
    const int e0 = blockIdx.x * EPB;
    for (int b = t; b < NBUK; b += 256) hist[b] = 0;
    __syncthreads();
    #pragma unroll
    for (int i = 0; i < EPB / 1024; ++i) {
      const int e = e0 + i * 1024 + t * 4;
      if (e < NNZ_E) {                       // NNZ % 4 == 0 -> whole int4 valid
        const int4 r4 = *reinterpret_cast<const int4*>(rows + e);
        atomicAdd(&hist[r4.x >> 8], 1); atomicAdd(&hist[r4.y >> 8], 1);
        atomicAdd(&hist[r4.z >> 8], 1); atomicAdd(&hist[r4.w >> 8], 1);
      }
    }
    __syncthreads();
    for (int b = t; b < NBUK; b += 256) {
      const int h = hist[b];
      base_s[b] = (h ? atomicAdd(&gcur[b], h) : 0) + b * BCAP;
      hist[b] = 0;
    }
    __syncthreads();
    #pragma unroll
    for (int i = 0; i < EPB / 1024; ++i) {
      const int e = e0 + i * 1024 + t * 4;
      if (e < NNZ_E) {
        const int4 r4 = *reinterpret_cast<const int4*>(rows + e);
        const int4 c4 = *reinterpret_cast<const int4*>(cols + e);
        #pragma unroll
        for (int k = 0; k < 4; ++k) {
          const int r = (k == 0) ? r4.x : (k == 1) ? r4.y : (k == 2) ? r4.z : r4.w;
          const int c = (k == 0) ? c4.x : (k == 1) ? c4.y : (k == 2) ? c4.z : c4.w;
          const int b = r >> 8;
          const int p = atomicAdd(&hist[b], 1);
          const int slot = base_s[b] + p;
          if (slot < (b + 1) * BCAP)              // statistical guard
            binArr[slot] = ((r & 255) << 24) | c; // col < 2^17 fits 24 bits
        }
      }
    }
  } else {
    // ---------------- prep branch ----------------
    const int gid = (blockIdx.x - BIN_BLOCKS) * 256 + t;
    if (DO_NF) {
      if (gid < NF_THREADS) {
        const int i = gid * 4;
        const f32x4 v = *reinterpret_cast<const f32x4*>(nf + i);
        f16x4 h;
        #pragma unroll
        for (int j = 0; j < 4; ++j) h[j] = (_Float16)v[j];
        *reinterpret_cast<f16x4*>(nfh + i) = h;
        return;
      }
    }
    const int idx = DO_NF ? (gid - NF_THREADS) : gid;
    if (idx < WB_ELEMS) {
      const int i  = idx & 7;
      const int l  = (idx >> 3) & 63;
      const int n  = (idx >> 9) & 3;
      const int kc = idx >> 11;
      const int k  = kc * 32 + ((l >> 4) << 3) + i;
      const int o  = n * 16 + (l & 15);
      Wb[idx] = (_Float16)W[o * K_DIM + k];
    }
  }
}

// -------- K_sortbucket: per bucket: hist -> cnt, scan -> row_start,
//          in-place scatter -> bucket-strided byte-offset CSR, log10 partial --------
__global__ __launch_bounds__(256) void k_sortbucket(int* __restrict__ bincsr,
                                                    const int* __restrict__ gcur,
                                                    int* __restrict__ cnt,
                                                    int* __restrict__ row_start,
                                                    float* __restrict__ partial) {
  __shared__ int se[BCAP];       // 20 KB edge stage
  __shared__ int hist[256];
  __shared__ int curs[256];
  __shared__ int sd[256];
  __shared__ float wsum[4];
  const int b = blockIdx.x, t = threadIdx.x;
  const int s0  = b * BCAP;
  const int len = min(gcur[b], BCAP);            // zero-based cursor
  for (int i = t; i < len; i += 256) se[i] = bincsr[s0 + i];
  hist[t] = 0;
  __syncthreads();
  for (int i = t; i < len; i += 256)
    atomicAdd(&hist[((unsigned)se[i]) >> 24], 1);
  __syncthreads();
  const int h = hist[t];
  const int r = (b << 8) + t;
  sd[t] = h;
  __syncthreads();
  #pragma unroll
  for (int off = 1; off < 256; off <<= 1) {
    int add = (t >= off) ? sd[t - off] : 0;
    __syncthreads();
    sd[t] += add;
    __syncthreads();
  }
  const int excl = sd[t] - h;
  curs[t] = excl;
  if (r < M_ROWS) {
    cnt[r] = h;
    row_start[r] = s0 + excl;
  }
  float ls = (r < M_ROWS) ? log10f((float)h + 2.0f) : 0.f;
  #pragma unroll
  for (int off = 32; off > 0; off >>= 1) ls += __shfl_xor(ls, off);
  if ((t & 63) == 0) wsum[t >> 6] = ls;
  __syncthreads();
  if (t == 0) partial[b] = wsum[0] + wsum[1] + wsum[2] + wsum[3];
  for (int i = t; i < len; i += 256) {
    const int e  = se[i];
    const int rl = (int)(((unsigned)e) >> 24);
    const int p  = atomicAdd(&curs[rl], 1);
    bincsr[s0 + p] = (e & 0x00FFFFFF) << 7;      // byte offset into f16 table
  }
}

// -------- K5: fused delta-reduce prologue + stats + MFMA epilogue.
//          ONE tile per block (VGPR 44 / ~40% occ — r14's 2-tile loop cost +27 µs). --------
template <bool F16NF>
__global__ __launch_bounds__(256) void k_main(
    const float* __restrict__ nf32, const _Float16* __restrict__ nfh,
    const int* __restrict__ csr, const int* __restrict__ rs,
    const int* __restrict__ cnt, const float* __restrict__ partial,
    const _Float16* __restrict__ Wb, const float* __restrict__ bias,
    float* __restrict__ out)
{
  __shared__ _Float16 xs[32][264];
  __shared__ float s_s[32];
  __shared__ float red[256];

  const int tid  = threadIdx.x;
  const int w    = tid >> 6;
  const int lane = tid & 63;
  const int g    = lane >> 4;        // group (row) within wave
  const int q    = lane & 15;        // lane within group
  const int h    = (lane >> 3) & 1;  // edge parity handled by this lane
  const int d    = lane & 7;         // dim block (8 dims)
  const int r0   = blockIdx.x * 32;
  const int d16  = d * 16;           // byte offset of dim block in f16 row

  // ---- prologue: delta = mean(log10(deg+2)) from 391 bucket partials ----
  float ps = 0.f;
  for (int i = tid; i < NBUK; i += 256) ps += partial[i];
  red[tid] = ps;
  __syncthreads();
  #pragma unroll
  for (int off = 128; off > 0; off >>= 1) {
    if (tid < off) red[tid] += red[tid + off];
    __syncthreads();
  }
  const float delta = red[0] / (float)M_ROWS;

  auto ld16 = [&](int off) -> f16x8 {
    if constexpr (F16NF) {
      return *reinterpret_cast<const f16x8*>((const char*)nfh + off + d16);
    } else {
      const char* p = (const char*)nf32 + (size_t)off * 2 + d * 32;
      const f32x4 a = *reinterpret_cast<const f32x4*>(p);
      const f32x4 c = *reinterpret_cast<const f32x4*>(p + 16);
      f16x8 x;
      #pragma unroll
      for (int j = 0; j < 4; ++j) { x[j] = (_Float16)a[j]; x[4 + j] = (_Float16)c[j]; }
      return x;
    }
  };

  auto xor8 = [&](f16x8 v) -> f16x8 {
    union { f16x8 hh; int ii[4]; } u;
    u.hh = v;
    #pragma unroll
    for (int k = 0; k < 4; ++k) u.ii[k] = __shfl_xor(u.ii[k], 8);
    return u.hh;
  };

  #pragma unroll
  for (int pass = 0; pass < 2; ++pass) {
    const int rl  = w * 8 + pass * 4 + g;
    const int r   = r0 + rl;
    const int js  = rs[r];
    const int len = cnt[r];            // true degree (>=1 by construction)
    const int full8 = len & ~7;        // edges covered by mask-free iterations
    const int tailn = len - full8;     // 0..7 edges left for the masked tail
    int mfull = full8, mtail = tailn;
    mfull = max(mfull, __shfl_xor(mfull, 16));
    mfull = max(mfull, __shfl_xor(mfull, 32));
    mtail = max(mtail, __shfl_xor(mtail, 16));
    mtail = max(mtail, __shfl_xor(mtail, 32));

    f16x8 hsum = {}; f16x8 hsq = {}; f16x8 hmx = {};
    f16x8 hmn = {(_Float16)INFINITY, (_Float16)INFINITY, (_Float16)INFINITY,
                 (_Float16)INFINITY, (_Float16)INFINITY, (_Float16)INFINITY,
                 (_Float16)INFINITY, (_Float16)INFINITY};

    const int jb = js + h;             // lane's index stream: edges h, h+2, ...

    // ---- mask-free full iterations (indices provably < len) ----
    for (int t = 0; t < mfull; t += 8) {
      if (t < full8) {                 // group-uniform
        const int i0 = csr[jb + t + 0];
        const int i1 = csr[jb + t + 2];
        const int i2 = csr[jb + t + 4];
        const int i3 = csr[jb + t + 6];
        const f16x8 x0 = ld16(i0), x1 = ld16(i1), x2 = ld16(i2), x3 = ld16(i3);
        hmx = __builtin_elementwise_max(hmx, x0);
        hmn = __builtin_elementwise_min(hmn, x0);
        hsum += x0; hsq += x0 * x0;
        hmx = __builtin_elementwise_max(hmx, x1);
        hmn = __builtin_elementwise_min(hmn, x1);
        hsum += x1; hsq += x1 * x1;
        hmx = __builtin_elementwise_max(hmx, x2);
        hmn = __builtin_elementwise_min(hmn, x2);
        hsum += x2; hsq += x2 * x2;
        hmx = __builtin_elementwise_max(hmx, x3);
        hmn = __builtin_elementwise_min(hmn, x3);
        hsum += x3; hsq += x3 * x3;
      }
    }

    // ---- clamped + masked tail (any-row-in-wave gate; idempotent rows safe) ----
    if (mtail > 0) {
      const int last = js + len - 1;
      const int e0 = full8 + 0 + h, e1 = full8 + 2 + h;
      const int e2 = full8 + 4 + h, e3 = full8 + 6 + h;
      const int i0 = csr[min(jb + full8 + 0, last)];
      const int i1 = csr[min(jb + full8 + 2, last)];
      const int i2 = csr[min(jb + full8 + 4, last)];
      const int i3 = csr[min(jb + full8 + 6, last)];
      const f16x8 x0 = ld16(i0), x1 = ld16(i1), x2 = ld16(i2), x3 = ld16(i3);
      const f16x8 z = {};
      const f16x8 m0 = (e0 < len) ? x0 : z;
      const f16x8 m1 = (e1 < len) ? x1 : z;
      const f16x8 m2 = (e2 < len) ? x2 : z;
      const f16x8 m3 = (e3 < len) ? x3 : z;
      hmx = __builtin_elementwise_max(hmx, x0);
      hmn = __builtin_elementwise_min(hmn, x0);
      hsum += m0; hsq += m0 * x0;
      hmx = __builtin_elementwise_max(hmx, x1);
      hmn = __builtin_elementwise_min(hmn, x1);
      hsum += m1; hsq += m1 * x1;
      hmx = __builtin_elementwise_max(hmx, x2);
      hmn = __builtin_elementwise_min(hmn, x2);
      hsum += m2; hsq += m2 * x2;
      hmx = __builtin_elementwise_max(hmx, x3);
      hmn = __builtin_elementwise_min(hmn, x3);
      hsum += m3; hsq += m3 * x3;
    }

    // ---- combine even/odd halves (lane <-> lane^8) ----
    hsum += xor8(hsum);
    hsq  += xor8(hsq);
    hmx = __builtin_elementwise_max(hmx, xor8(hmx));
    hmn = __builtin_elementwise_min(hmn, xor8(hmn));

    const float dg  = (float)len;
    const float inv = 1.0f / fmaxf(dg, 1.0f);
    f16x8 hmean, hstd;
    #pragma unroll
    for (int i = 0; i < 8; ++i) {
      const float mean = (float)hsum[i] * inv;
      const float sqm  = (float)hsq[i] * inv;
      const float var  = fmaxf(sqm - mean * mean, 0.f);
      hmean[i] = (_Float16)mean;
      hstd[i]  = (_Float16)sqrtf(var);
    }
    if (h == 0) {                      // lanes q<8 write; halves identical
      *reinterpret_cast<f16x8*>(&xs[rl][0 * 64 + d * 8]) = hmean;
      *reinterpret_cast<f16x8*>(&xs[rl][1 * 64 + d * 8]) = hmx;
      *reinterpret_cast<f16x8*>(&xs[rl][2 * 64 + d * 8]) = hmn;
      *reinterpret_cast<f16x8*>(&xs[rl][3 * 64 + d * 8]) = hstd;
      if (q == 0) s_s[rl] = log10f(dg + 2.0f) / delta;
    }
  }
  __syncthreads();

  // ---- phase 2: wave w -> cols w*16..+16, row tiles 0..15 / 16..31 ----
  f32x4 acc0 = {0.f, 0.f, 0.f, 0.f}, acc1 = {0.f, 0.f, 0.f, 0.f};
  const int khi = lane >> 4;
  const float sA = s_s[q];
  const float sB = s_s[16 + q];
  const f16x8 sA8  = (f16x8)(_Float16)sA;
  const f16x8 isA8 = (f16x8)(_Float16)(1.0f / sA);
  const f16x8 sB8  = (f16x8)(_Float16)sB;
  const f16x8 isB8 = (f16x8)(_Float16)(1.0f / sB);

  #pragma unroll
  for (int kc = 0; kc < NCHUNK; ++kc) {
    const int kb = kc >> 1;
    const int a  = kb / 3;
    const int tt = kb - 3 * a;
    const int off = a * 64 + ((kc & 1) << 5) + (khi << 3);
    f16x8 a0 = *reinterpret_cast<const f16x8*>(&xs[q][off]);
    f16x8 a1 = *reinterpret_cast<const f16x8*>(&xs[16 + q][off]);
    if (tt == 1) { a0 = a0 * sA8;  a1 = a1 * sB8; }
    if (tt == 2) { a0 = a0 * isA8; a1 = a1 * isB8; }
    const f16x8 bf = *reinterpret_cast<const f16x8*>(Wb + ((size_t)(kc * 4 + w) * 64 + lane) * 8);
    acc0 = __builtin_amdgcn_mfma_f32_16x16x32_f16(a0, bf, acc0, 0, 0, 0);
    acc1 = __builtin_amdgcn_mfma_f32_16x16x32_f16(a1, bf, acc1, 0, 0, 0);
  }

  const int col = w * 16 + q;
  const float bv = bias[col];
  #pragma unroll
  for (int i = 0; i < 4; ++i) {
    const int rr = khi * 4 + i;
    float v = acc0[i] + bv;
    v = (v >= 0.f) ? v : NEG_SLOPE * v;
    out[(size_t)(r0 + rr) * 64 + col] = v;
    float u = acc1[i] + bv;
    u = (u >= 0.f) ? u : NEG_SLOPE * u;
    out[(size_t)(r0 + 16 + rr) * 64 + col] = u;
  }
}

extern "C" void kernel_launch(void* const* d_in, const int* in_sizes, int n_in,
                              void* d_out, int out_size, void* d_ws, size_t ws_size,
                              hipStream_t stream) {
  const int*   rows = (const int*)d_in[0];
  const int*   cols = (const int*)d_in[1];
  const float* nf   = (const float*)d_in[3];
  const float* W    = (const float*)d_in[4];
  const float* bias = (const float*)d_in[5];
  float* out = (float*)d_out;

  char* ws = (char*)d_ws;
  int*      cnt       = (int*)(ws + OFF_CNT);
  int*      row_start = (int*)(ws + OFF_RS);
  float*    partial   = (float*)(ws + OFF_PART);
  int*      gcur      = (int*)(ws + OFF_GCUR);
  int*      bincsr    = (int*)(ws + OFF_BINCSR);
  _Float16* Wb        = (_Float16*)(ws + OFF_WB);
  _Float16* nfh       = (_Float16*)(ws + OFF_NFH);

  const bool f16path = (ws_size >= WS_NEEDED);

  hipMemsetAsync(gcur, 0, NBUK * 4, stream);     // zero-based bucket cursors

  if (f16path) {
    const int tail = (NF_THREADS + WB_ELEMS + 255) / 256;            // 6442
    k_prep2<true><<<BIN_BLOCKS + tail, 256, 0, stream>>>(rows, cols, gcur, bincsr,
                                                         nf, nfh, W, Wb);
  } else {
    const int tail = (WB_ELEMS + 255) / 256;                         // 192
    k_prep2<false><<<BIN_BLOCKS + tail, 256, 0, stream>>>(rows, cols, gcur, bincsr,
                                                          nf, nfh, W, Wb);
  }
  k_sortbucket<<<NBUK, 256, 0, stream>>>(bincsr, gcur, cnt, row_start, partial);
  if (f16path)
    k_main<true><<<M_ROWS / 32, 256, 0, stream>>>(nf, nfh, bincsr, row_start, cnt,
                                                  partial, Wb, bias, out);
  else
    k_main<false><<<M_ROWS / 32, 256, 0, stream>>>(nf, nfh, bincsr, row_start, cnt,
                                                   partial, Wb, bias, out);
}